// Round 10
// baseline (357.255 us; speedup 1.0000x reference)
//
#include <hip/hip_runtime.h>
#include <hip/hip_bf16.h>

typedef unsigned short u16;
typedef __attribute__((ext_vector_type(8))) short bf16x8;
typedef __attribute__((ext_vector_type(4))) float f32x4;

#define N_TOK 4096
#define DMODEL 3072
#define NH 16
#define DHEAD 64
#define INNER 1024
#define SCALE_LOG2E 0.18033688011112042f  /* (1/8) * log2(e) */

__device__ __forceinline__ u16 f2bf(float f) {
    union { float f; unsigned u; } un; un.f = f;
    unsigned r = un.u + 0x7fffu + ((un.u >> 16) & 1u);
    return (u16)(r >> 16);
}
__device__ __forceinline__ float bf2f(u16 u) {
    union { unsigned u; float f; } x; x.u = ((unsigned)u) << 16; return x.f;
}
// pack two f32 -> two bf16 (round-half-up) in 3 VALU ops; a -> low 16
__device__ __forceinline__ unsigned pk2bf(float a, float b) {
    union { float f; unsigned u; } ua, ub; ua.f = a; ub.f = b;
    return __builtin_amdgcn_perm(ub.u + 0x8000u, ua.u + 0x8000u, 0x07060302u);
}
__device__ __forceinline__ void load_lds16(const u16* g, u16* l) {
    __builtin_amdgcn_global_load_lds(
        (const __attribute__((address_space(1))) unsigned int*)g,
        (__attribute__((address_space(3))) unsigned int*)l, 16, 0, 0);
}

// Build PV B-operand in-register from packed exp2(S^T) words.
// Output: lane (l15,quad) holds keys [8*quad, 8*quad+8) for col q=l15.
__device__ __forceinline__ bf16x8 build_bp(unsigned u0, unsigned u1,
                                           unsigned w0, unsigned w1) {
    auto a = __builtin_amdgcn_permlane32_swap(u0, w0, false, false);
    auto b = __builtin_amdgcn_permlane16_swap(a[0], a[1], false, false);
    auto c = __builtin_amdgcn_permlane32_swap(u1, w1, false, false);
    auto d = __builtin_amdgcn_permlane16_swap(c[0], c[1], false, false);
    union { unsigned w[4]; bf16x8 v; } r;
    r.w[0] = b[0]; r.w[1] = d[0]; r.w[2] = b[1]; r.w[3] = d[1];
    return r.v;
}

// ------- Fused prep: LN rows (blocks 0..4095), wq cvt (4096..6143), --------
// ------- wo cvt (6144..6655). --------
__global__ __launch_bounds__(256) void prep(const float* __restrict__ x,
                                            const float* __restrict__ g,
                                            const float* __restrict__ b,
                                            u16* __restrict__ xn,
                                            const float* __restrict__ w_qkv,
                                            u16* __restrict__ wq,
                                            const float* __restrict__ w_out,
                                            u16* __restrict__ wo) {
    int bid = blockIdx.x;
    int tid = threadIdx.x;
    if (bid < 4096) {
        int row = bid;
        const float4* xr = (const float4*)(x + (size_t)row * DMODEL);
        float4 v[3];
        float s = 0.f, ss = 0.f;
#pragma unroll
        for (int i = 0; i < 3; ++i) {
            v[i] = xr[i * 256 + tid];
            s  += v[i].x + v[i].y + v[i].z + v[i].w;
            ss += v[i].x * v[i].x + v[i].y * v[i].y + v[i].z * v[i].z + v[i].w * v[i].w;
        }
#pragma unroll
        for (int off = 32; off; off >>= 1) {
            s  += __shfl_xor(s, off);
            ss += __shfl_xor(ss, off);
        }
        __shared__ float red[8];
        int wid = tid >> 6, lane = tid & 63;
        if (lane == 0) { red[wid] = s; red[wid + 4] = ss; }
        __syncthreads();
        s  = red[0] + red[1] + red[2] + red[3];
        ss = red[4] + red[5] + red[6] + red[7];
        float mean = s * (1.f / DMODEL);
        float var  = ss * (1.f / DMODEL) - mean * mean;
        float rstd = rsqrtf(var + 1e-5f);
        ushort4* orow = (ushort4*)(xn + (size_t)row * DMODEL);
#pragma unroll
        for (int i = 0; i < 3; ++i) {
            float4 gg = ((const float4*)g)[i * 256 + tid];
            float4 bb = ((const float4*)b)[i * 256 + tid];
            ushort4 o;
            o.x = f2bf((v[i].x - mean) * rstd * gg.x + bb.x);
            o.y = f2bf((v[i].y - mean) * rstd * gg.y + bb.y);
            o.z = f2bf((v[i].z - mean) * rstd * gg.z + bb.z);
            o.w = f2bf((v[i].w - mean) * rstd * gg.w + bb.w);
            orow[i * 256 + tid] = o;
        }
    } else if (bid < 4096 + 2048) {
        const int n4 = 3 * INNER * DMODEL / 4;
        for (int i = (bid - 4096) * 256 + tid; i < n4; i += 2048 * 256) {
            float4 v = ((const float4*)w_qkv)[i];
            ushort4 o;
            o.x = f2bf(v.x); o.y = f2bf(v.y); o.z = f2bf(v.z); o.w = f2bf(v.w);
            ((ushort4*)wq)[i] = o;
        }
    } else {
        const int n4 = DMODEL * INNER / 4;
        for (int i = (bid - 6144) * 256 + tid; i < n4; i += 512 * 256) {
            float4 v = ((const float4*)w_out)[i];
            ushort4 o;
            o.x = f2bf(v.x); o.y = f2bf(v.y); o.z = f2bf(v.z); o.w = f2bf(v.w);
            ((ushort4*)wo)[i] = o;
        }
    }
}

// ============ GEMM 256x256 8-phase (T2+T3+T4+T5), C = A * B^T ============
// MODE 0: C = f32 (out-proj, unchanged control).
// MODE 2: QKV-fused epilogue — RoPE(Q,K) via lane-pair shfl + direct write
// to Qr/Kr [h][n][d]; V written transposed to Vt [h][d][n] (ushort4 of 4
// consecutive rows). Main loop/staging/sync byte-identical to R2-R9.

#define VM6 asm volatile("s_waitcnt vmcnt(6)" ::: "memory")
#define VM4 asm volatile("s_waitcnt vmcnt(4)" ::: "memory")
#define VM0 asm volatile("s_waitcnt vmcnt(0)" ::: "memory")
#define LGK8 asm volatile("s_waitcnt lgkmcnt(8)" ::: "memory")
#define NOPS ((void)0)

#define ST_A(d, h, t) do { \
    load_lds16(pA##h##0 + (size_t)(t) * 64, &lds[(d) * 16384 + (h) * 8192 + dq]); \
    load_lds16(pA##h##1 + (size_t)(t) * 64, &lds[(d) * 16384 + (h) * 8192 + dq + 512]); \
  } while (0)
#define ST_B(d, h, t) do { \
    load_lds16(pB##h##0 + (size_t)(t) * 64, &lds[32768 + (d) * 16384 + (h) * 8192 + dq]); \
    load_lds16(pB##h##1 + (size_t)(t) * 64, &lds[32768 + (d) * 16384 + (h) * 8192 + dq + 512]); \
  } while (0)

#define PHASE(d, p, STAGE, PRE, POST) do { \
    bf16x8 afr[2][2]; \
    if ((p) == 0) { \
      _Pragma("unroll") for (int nf = 0; nf < 4; ++nf) { \
        bfr[nf][0] = *(const bf16x8*)&lds[(d) * 16384 + baseB + nf * 1024 + c0]; \
        bfr[nf][1] = *(const bf16x8*)&lds[(d) * 16384 + baseB + nf * 1024 + c1]; \
      } \
    } \
    _Pragma("unroll") for (int mfl = 0; mfl < 2; ++mfl) { \
      afr[mfl][0] = *(const bf16x8*)&lds[(d) * 16384 + (p) * 4096 + mfl * 1024 + baseA + c0]; \
      afr[mfl][1] = *(const bf16x8*)&lds[(d) * 16384 + (p) * 4096 + mfl * 1024 + baseA + c1]; \
    } \
    STAGE; \
    PRE; \
    __builtin_amdgcn_s_barrier(); \
    asm volatile("s_waitcnt lgkmcnt(0)" ::: "memory"); \
    __builtin_amdgcn_sched_barrier(0); \
    __builtin_amdgcn_s_setprio(1); \
    _Pragma("unroll") for (int mfl = 0; mfl < 2; ++mfl) \
      _Pragma("unroll") for (int nf = 0; nf < 4; ++nf) { \
        acc[(p) * 2 + mfl][nf] = __builtin_amdgcn_mfma_f32_16x16x32_bf16(afr[mfl][0], bfr[nf][0], acc[(p) * 2 + mfl][nf], 0, 0, 0); \
        acc[(p) * 2 + mfl][nf] = __builtin_amdgcn_mfma_f32_16x16x32_bf16(afr[mfl][1], bfr[nf][1], acc[(p) * 2 + mfl][nf], 0, 0, 0); \
      } \
    __builtin_amdgcn_s_setprio(0); \
    POST; \
    __builtin_amdgcn_s_barrier(); \
  } while (0)

template <int MODE>
__global__ __launch_bounds__(512, 2) void gemm256(const u16* __restrict__ A,
                                                  const u16* __restrict__ B,
                                                  void* __restrict__ C,
                                                  int M, int Nn, int K,
                                                  const float* __restrict__ pe,
                                                  u16* __restrict__ Qr,
                                                  u16* __restrict__ Kr,
                                                  u16* __restrict__ Vt) {
    __shared__ u16 lds[65536];   // A: [2][256][64] @0 ; B: same @32768 (128 KiB)
    const int tid = threadIdx.x;
    const int lane = tid & 63, wid = tid >> 6;
    const int wm = wid >> 2, wn = wid & 3;
    const int l15 = lane & 15, quad = lane >> 4;
    const int sw = l15 & 7;

    // XCD-aware bijective swizzle (gridDim.x % 8 == 0)
    int nbx = Nn >> 8;
    int cpx = gridDim.x >> 3;
    int wg = (blockIdx.x & 7) * cpx + (blockIdx.x >> 3);
    int m0 = (wg / nbx) << 8, n0 = (wg % nbx) << 8;

    // per-thread ds_read bases (u16 units) and swizzled chunk offsets
    const int baseA = wm * 2048 + l15 * 64;
    const int baseB = 32768 + wn * 4096 + l15 * 64;
    const int c0 = (quad ^ sw) * 8;
    const int c1 = ((4 + quad) ^ sw) * 8;
    const int dq = wid * 1024;                 // stage LDS base (j adds 512)

    // stage source pointers: LDS row ell -> global row, pre-swizzled col
    const u16 *pA00, *pA01, *pA10, *pA11, *pB00, *pB01, *pB10, *pB11;
    {
        int scol = ((lane & 7) ^ (lane >> 3)) * 8;
#define MKSRC(h, j, PA, PB) { \
        int ell = (h) * 128 + (wid * 2 + (j)) * 8 + (lane >> 3); \
        int g = ell >> 6, wmh = (ell >> 5) & 1, r = ell & 31; \
        PA = A + (size_t)(m0 + wmh * 128 + g * 32 + r) * K + scol; \
        PB = B + (size_t)(n0 + ell) * K + scol; }
        MKSRC(0, 0, pA00, pB00) MKSRC(0, 1, pA01, pB01)
        MKSRC(1, 0, pA10, pB10) MKSRC(1, 1, pA11, pB11)
#undef MKSRC
    }

    f32x4 acc[8][4];
    f32x4 zero4 = {0.f, 0.f, 0.f, 0.f};
#pragma unroll
    for (int i = 0; i < 8; ++i)
#pragma unroll
        for (int j = 0; j < 4; ++j) acc[i][j] = zero4;
    bf16x8 bfr[4][2];

    // prologue: tile0 (4 halves) -> buf0, tile1 (B0,B1,A0) -> buf1
    ST_B(0, 0, 0); ST_B(0, 1, 0); ST_A(0, 0, 0); ST_A(0, 1, 0);
    ST_B(1, 0, 1); ST_B(1, 1, 1); ST_A(1, 0, 1);
    VM6;                                   // tile0 landed; 3 halves in flight
    __builtin_amdgcn_s_barrier();

    const int NIT = (K >> 7) - 1;          // T/2 - 1 iterations
    for (int i = 0; i < NIT; ++i) {
        int t = 2 * i;
        PHASE(0, 0, ST_A(1, 1, t + 1), LGK8, NOPS);
        PHASE(0, 1, ST_B(0, 0, t + 2), NOPS, NOPS);
        PHASE(0, 2, ST_B(0, 1, t + 2), NOPS, NOPS);
        PHASE(0, 3, ST_A(0, 0, t + 2), NOPS, VM6);
        PHASE(1, 0, ST_A(0, 1, t + 2), LGK8, NOPS);
        PHASE(1, 1, ST_B(1, 0, t + 3), NOPS, NOPS);
        PHASE(1, 2, ST_B(1, 1, t + 3), NOPS, NOPS);
        PHASE(1, 3, ST_A(1, 0, t + 3), NOPS, VM6);
    }
    {   // epilogue: tiles T-2 (buf0), T-1 (buf1); only (T-1).A1 left to stage
        int T = K >> 6;
        PHASE(0, 0, ST_A(1, 1, T - 1), LGK8, NOPS);
        PHASE(0, 1, NOPS, NOPS, NOPS);
        PHASE(0, 2, NOPS, NOPS, NOPS);
        PHASE(0, 3, NOPS, NOPS, VM0);
        PHASE(1, 0, NOPS, LGK8, NOPS);
        PHASE(1, 1, NOPS, NOPS, NOPS);
        PHASE(1, 2, NOPS, NOPS, NOPS);
        PHASE(1, 3, NOPS, NOPS, NOPS);
    }

    if (MODE == 0) {
        // C write: rr = m0+wm*128+mf*16+quad*4+r ; cc = n0+wn*64+nf*16+l15
#pragma unroll
        for (int mf = 0; mf < 8; ++mf)
#pragma unroll
            for (int nf = 0; nf < 4; ++nf)
#pragma unroll
                for (int r = 0; r < 4; ++r) {
                    int rr = m0 + wm * 128 + mf * 16 + quad * 4 + r;
                    int cc = n0 + wn * 64 + nf * 16 + l15;
                    ((float*)C)[(size_t)rr * Nn + cc] = acc[mf][nf][r];
                }
    } else if (n0 < 2048) {
        // Q or K tile: apply RoPE (col pairs 2i,2i+1 = lane pairs l15^1)
        const int isQ = (n0 < 1024);
        const float scl = isQ ? SCALE_LOG2E : 1.f;
        u16* dst = isQ ? Qr : Kr;
#pragma unroll
        for (int mf = 0; mf < 8; ++mf)
#pragma unroll
            for (int nf = 0; nf < 4; ++nf) {
                int cc = n0 + wn * 64 + nf * 16 + l15;
                int hh = (cc & 1023) >> 6;
                int ii = (cc & 63) >> 1;
                int jj = cc & 1;
#pragma unroll
                for (int r = 0; r < 4; ++r) {
                    int rr = m0 + wm * 128 + mf * 16 + quad * 4 + r;
                    float v = acc[mf][nf][r];
                    float vp = __shfl_xor(v, 1);
                    float v0 = jj ? vp : v;
                    float v1 = jj ? v : vp;
                    const float* pw = pe + (size_t)rr * 128 + ii * 4 + jj * 2;
                    float ov = (pw[0] * v0 + pw[1] * v1) * scl;
                    dst[((size_t)hh * N_TOK + rr) * 64 + (cc & 63)] = f2bf(ov);
                }
            }
    } else {
        // V tile: write transposed Vt[h][d][n] — 4 consecutive rows/ushort4
#pragma unroll
        for (int mf = 0; mf < 8; ++mf)
#pragma unroll
            for (int nf = 0; nf < 4; ++nf) {
                int cc = n0 + wn * 64 + nf * 16 + l15;
                int hh = (cc - 2048) >> 6, dd = cc & 63;
                int rr = m0 + wm * 128 + mf * 16 + quad * 4;
                ushort4 o4;
                o4.x = f2bf(acc[mf][nf][0]); o4.y = f2bf(acc[mf][nf][1]);
                o4.z = f2bf(acc[mf][nf][2]); o4.w = f2bf(acc[mf][nf][3]);
                *(ushort4*)&Vt[((size_t)hh * 64 + dd) * N_TOK + rr] = o4;
            }
    }
}

// ---------------- Flash attention: R9 (unchanged control) -----------------
// 4 waves x 32 q-rows, QBLK=128, 2 blocks/CU; 3x16KB K/V rotation, split
// lgkm(8)/lgkm(0) waits, counted vmcnt(4), in-register P exchange.

#define FA_STAGE3(dst, kt) do { \
    load_lds16(&Kh[(size_t)((kt) + krow) * DHEAD + csw], &lds_all[(dst) + kbase]); \
    load_lds16(&Kh[(size_t)((kt) + krow + 8) * DHEAD + csw], &lds_all[(dst) + kbase + 512]); \
    load_lds16(&Vh[(size_t)krow * N_TOK + (kt) + csw], &lds_all[(dst) + 4096 + kbase]); \
    load_lds16(&Vh[(size_t)(krow + 8) * N_TOK + (kt) + csw], &lds_all[(dst) + 4096 + kbase + 512]); \
  } while (0)

__global__ __launch_bounds__(256, 2) void flash_attn(const u16* __restrict__ Q,
                                                     const u16* __restrict__ K,
                                                     const u16* __restrict__ Vt,
                                                     u16* __restrict__ O) {
    __shared__ u16 lds_all[24576];           // 48 KB: 3 x 16KB K/V rotation
    int tid = threadIdx.x, lane = tid & 63, wid = tid >> 6;
    int l15 = lane & 15, quad = lane >> 4;
    int sw = l15 & 7;
    int h = blockIdx.y;
    int q0 = blockIdx.x * 128 + wid * 32;
    const u16* Qh = Q + (size_t)h * N_TOK * DHEAD;
    const u16* Kh = K + (size_t)h * N_TOK * DHEAD;
    const u16* Vh = Vt + (size_t)h * DHEAD * N_TOK;

    f32x4 zero4 = {0.f, 0.f, 0.f, 0.f};
    bf16x8 ones;
#pragma unroll
    for (int i = 0; i < 8; ++i) ones[i] = (short)0x3F80;  // bf16 1.0

    // Q fragments (B operand): B[n=q=l15][k=dhead]
    bf16x8 aq[2][2];
#pragma unroll
    for (int mtQ = 0; mtQ < 2; ++mtQ)
#pragma unroll
        for (int kc = 0; kc < 2; ++kc)
            aq[mtQ][kc] = *(const bf16x8*)&Qh[(size_t)(q0 + mtQ * 16 + l15) * DHEAD + kc * 32 + quad * 8];

    f32x4 o[2][4], lacc[2];
#pragma unroll
    for (int mtQ = 0; mtQ < 2; ++mtQ) {
#pragma unroll
        for (int dt = 0; dt < 4; ++dt) o[mtQ][dt] = zero4;
        lacc[mtQ] = zero4;
    }

    // staging: wave stages K rows [wid*16, wid*16+16) and V rows same range
    int rowoff = lane >> 3;                      // 0..7
    int krow = wid * 16 + rowoff;                // 0..63 (with +8 variant)
    int kbase = wid * 1024;                      // u16: wid*16 rows * 64
    int csw = ((lane & 7) ^ rowoff) * 8;         // swizzled source column (u16)

    // prologue: tiles 0,1 -> bufs 0,1; wait tile0 (tile1's 4 loads in flight)
    FA_STAGE3(0, 0);
    FA_STAGE3(8192, 64);
    VM4;
    __builtin_amdgcn_s_barrier();
    __builtin_amdgcn_sched_barrier(0);

    int cur = 0;
    for (int t = 0; t < 64; ++t) {
        int stg = cur + 16384; if (stg >= 24576) stg -= 24576;  // (t+2)%3
        bf16x8 bk[4][2], av[4][2];
#pragma unroll
        for (int tt = 0; tt < 4; ++tt)
#pragma unroll
            for (int kc = 0; kc < 2; ++kc)
                bk[tt][kc] = *(const bf16x8*)&lds_all[cur + (tt * 16 + l15) * 64 + (((kc * 4 + quad) ^ sw) * 8)];
        __builtin_amdgcn_sched_barrier(0);
#pragma unroll
        for (int tt = 0; tt < 4; ++tt)
#pragma unroll
            for (int kc = 0; kc < 2; ++kc)
                av[tt][kc] = *(const bf16x8*)&lds_all[cur + 4096 + (tt * 16 + l15) * 64 + (((kc * 4 + quad) ^ sw) * 8)];
        __builtin_amdgcn_sched_barrier(0);
        if (t < 62) FA_STAGE3(stg, (t + 2) * 64);
        asm volatile("s_waitcnt lgkmcnt(8)" ::: "memory");   // bk ready; av in flight
        __builtin_amdgcn_sched_barrier(0);

        bf16x8 bp[2][2];
#pragma unroll
        for (int mtQ = 0; mtQ < 2; ++mtQ) {
            f32x4 s[4];
            __builtin_amdgcn_s_setprio(1);
#pragma unroll
            for (int ntK = 0; ntK < 4; ++ntK) {
                f32x4 t0 = __builtin_amdgcn_mfma_f32_16x16x32_bf16(bk[ntK][0], aq[mtQ][0], zero4, 0, 0, 0);
                s[ntK] = __builtin_amdgcn_mfma_f32_16x16x32_bf16(bk[ntK][1], aq[mtQ][1], t0, 0, 0, 0);
            }
            __builtin_amdgcn_s_setprio(0);
            unsigned pw[4][2];
#pragma unroll
            for (int ntK = 0; ntK < 4; ++ntK) {
                pw[ntK][0] = pk2bf(__builtin_amdgcn_exp2f(s[ntK][0]), __builtin_amdgcn_exp2f(s[ntK][1]));
                pw[ntK][1] = pk2bf(__builtin_amdgcn_exp2f(s[ntK][2]), __builtin_amdgcn_exp2f(s[ntK][3]));
            }
            bp[mtQ][0] = build_bp(pw[0][0], pw[0][1], pw[1][0], pw[1][1]);
            bp[mtQ][1] = build_bp(pw[2][0], pw[2][1], pw[3][0], pw[3][1]);
        }

        asm volatile("s_waitcnt lgkmcnt(0)" ::: "memory");   // av ready
        __builtin_amdgcn_sched_barrier(0);
        __builtin_amdgcn_s_setprio(1);
#pragma unroll
        for (int mtQ = 0; mtQ < 2; ++mtQ) {
            lacc[mtQ] = __builtin_amdgcn_mfma_f32_16x16x32_bf16(ones, bp[mtQ][0], lacc[mtQ], 0, 0, 0);
            lacc[mtQ] = __builtin_amdgcn_mfma_f32_16x16x32_bf16(ones, bp[mtQ][1], lacc[mtQ], 0, 0, 0);
#pragma unroll
            for (int dt = 0; dt < 4; ++dt) {
                o[mtQ][dt] = __builtin_amdgcn_mfma_f32_16x16x32_bf16(av[dt][0], bp[mtQ][0], o[mtQ][dt], 0, 0, 0);
                o[mtQ][dt] = __builtin_amdgcn_mfma_f32_16x16x32_bf16(av[dt][1], bp[mtQ][1], o[mtQ][dt], 0, 0, 0);
            }
        }
        __builtin_amdgcn_s_setprio(0);

        if (t < 62) { VM4; } else if (t == 62) { VM0; }
        __builtin_amdgcn_s_barrier();
        __builtin_amdgcn_sched_barrier(0);
        cur += 8192; if (cur >= 24576) cur -= 24576;
    }

    // epilogue: transpose O^T -> O via per-wave LDS scratch, then coalesced write
    __syncthreads();
    u16* scratch = lds_all + wid * 2048;     // [q 32][d 64] per wave (4 KB)
#pragma unroll
    for (int mtQ = 0; mtQ < 2; ++mtQ) {
        float rl = 1.f / lacc[mtQ][0];
#pragma unroll
        for (int dt = 0; dt < 4; ++dt) {
            uint2 ov;
            ov.x = pk2bf(o[mtQ][dt][0] * rl, o[mtQ][dt][1] * rl);
            ov.y = pk2bf(o[mtQ][dt][2] * rl, o[mtQ][dt][3] * rl);
            *(uint2*)&scratch[(mtQ * 16 + l15) * 64 + dt * 16 + quad * 4] = ov;
        }
    }
    __syncthreads();
#pragma unroll
    for (int p = 0; p < 4; ++p) {
        int q_local = p * 8 + (lane >> 3);
        int dcol = (lane & 7) * 8;
        bf16x8 v = *(const bf16x8*)&scratch[q_local * 64 + dcol];
        *(bf16x8*)&O[(size_t)(q0 + q_local) * INNER + h * 64 + dcol] = v;
    }
}

extern "C" void kernel_launch(void* const* d_in, const int* in_sizes, int n_in,
                              void* d_out, int out_size, void* d_ws, size_t ws_size,
                              hipStream_t stream) {
    const float* x     = (const float*)d_in[0];
    const float* pe    = (const float*)d_in[1];
    const float* w_qkv = (const float*)d_in[2];
    const float* w_out = (const float*)d_in[3];
    const float* ln_g  = (const float*)d_in[4];
    const float* ln_b  = (const float*)d_in[5];
    float* out = (float*)d_out;

    char* ws = (char*)d_ws;
    u16* xn  = (u16*)ws;  ws += (size_t)N_TOK * DMODEL * 2;
    u16* wq  = (u16*)ws;  ws += (size_t)3 * INNER * DMODEL * 2;
    u16* wo  = (u16*)ws;  ws += (size_t)DMODEL * INNER * 2;
    u16* Qr  = (u16*)ws;  ws += (size_t)NH * N_TOK * DHEAD * 2;
    u16* Kr  = (u16*)ws;  ws += (size_t)NH * N_TOK * DHEAD * 2;
    u16* Vt  = (u16*)ws;  ws += (size_t)NH * DHEAD * N_TOK * 2;
    u16* Ob  = (u16*)ws;  ws += (size_t)N_TOK * INNER * 2;

    prep<<<4096 + 2048 + 512, 256, 0, stream>>>(x, ln_g, ln_b, xn, w_qkv, wq, w_out, wo);
    gemm256<2><<<dim3((N_TOK / 256) * (DMODEL / 256)), 512, 0, stream>>>(
        xn, wq, nullptr, N_TOK, DMODEL, DMODEL, pe, Qr, Kr, Vt);
    flash_attn<<<dim3(N_TOK / 128, NH), 256, 0, stream>>>(Qr, Kr, Vt, Ob);
    gemm256<0><<<dim3((N_TOK / 256) * (DMODEL / 256)), 512, 0, stream>>>(
        Ob, wo, out, N_TOK, DMODEL, INNER, nullptr, nullptr, nullptr, nullptr);
}

// Round 11
// 348.873 us; speedup vs baseline: 1.0240x; 1.0240x over previous
//
#include <hip/hip_runtime.h>
#include <hip/hip_bf16.h>

typedef unsigned short u16;
typedef __attribute__((ext_vector_type(8))) short bf16x8;
typedef __attribute__((ext_vector_type(4))) float f32x4;

#define N_TOK 4096
#define DMODEL 3072
#define NH 16
#define DHEAD 64
#define INNER 1024
#define SCALE_LOG2E 0.18033688011112042f  /* (1/8) * log2(e) */

__device__ __forceinline__ u16 f2bf(float f) {
    union { float f; unsigned u; } un; un.f = f;
    unsigned r = un.u + 0x7fffu + ((un.u >> 16) & 1u);
    return (u16)(r >> 16);
}
__device__ __forceinline__ float bf2f(u16 u) {
    union { unsigned u; float f; } x; x.u = ((unsigned)u) << 16; return x.f;
}
// pack two f32 -> two bf16 (round-half-up) in 3 VALU ops; a -> low 16
__device__ __forceinline__ unsigned pk2bf(float a, float b) {
    union { float f; unsigned u; } ua, ub; ua.f = a; ub.f = b;
    return __builtin_amdgcn_perm(ub.u + 0x8000u, ua.u + 0x8000u, 0x07060302u);
}
__device__ __forceinline__ void load_lds16(const u16* g, u16* l) {
    __builtin_amdgcn_global_load_lds(
        (const __attribute__((address_space(1))) unsigned int*)g,
        (__attribute__((address_space(3))) unsigned int*)l, 16, 0, 0);
}

// Build PV B-operand in-register from packed exp2(S^T) words.
// Output: lane (l15,quad) holds keys [8*quad, 8*quad+8) for col q=l15.
__device__ __forceinline__ bf16x8 build_bp(unsigned u0, unsigned u1,
                                           unsigned w0, unsigned w1) {
    auto a = __builtin_amdgcn_permlane32_swap(u0, w0, false, false);
    auto b = __builtin_amdgcn_permlane16_swap(a[0], a[1], false, false);
    auto c = __builtin_amdgcn_permlane32_swap(u1, w1, false, false);
    auto d = __builtin_amdgcn_permlane16_swap(c[0], c[1], false, false);
    union { unsigned w[4]; bf16x8 v; } r;
    r.w[0] = b[0]; r.w[1] = d[0]; r.w[2] = b[1]; r.w[3] = d[1];
    return r.v;
}

// ------- Fused prep: LN rows (blocks 0..4095), wq cvt (4096..6143), --------
// ------- wo cvt (6144..6655). --------
__global__ __launch_bounds__(256) void prep(const float* __restrict__ x,
                                            const float* __restrict__ g,
                                            const float* __restrict__ b,
                                            u16* __restrict__ xn,
                                            const float* __restrict__ w_qkv,
                                            u16* __restrict__ wq,
                                            const float* __restrict__ w_out,
                                            u16* __restrict__ wo) {
    int bid = blockIdx.x;
    int tid = threadIdx.x;
    if (bid < 4096) {
        int row = bid;
        const float4* xr = (const float4*)(x + (size_t)row * DMODEL);
        float4 v[3];
        float s = 0.f, ss = 0.f;
#pragma unroll
        for (int i = 0; i < 3; ++i) {
            v[i] = xr[i * 256 + tid];
            s  += v[i].x + v[i].y + v[i].z + v[i].w;
            ss += v[i].x * v[i].x + v[i].y * v[i].y + v[i].z * v[i].z + v[i].w * v[i].w;
        }
#pragma unroll
        for (int off = 32; off; off >>= 1) {
            s  += __shfl_xor(s, off);
            ss += __shfl_xor(ss, off);
        }
        __shared__ float red[8];
        int wid = tid >> 6, lane = tid & 63;
        if (lane == 0) { red[wid] = s; red[wid + 4] = ss; }
        __syncthreads();
        s  = red[0] + red[1] + red[2] + red[3];
        ss = red[4] + red[5] + red[6] + red[7];
        float mean = s * (1.f / DMODEL);
        float var  = ss * (1.f / DMODEL) - mean * mean;
        float rstd = rsqrtf(var + 1e-5f);
        ushort4* orow = (ushort4*)(xn + (size_t)row * DMODEL);
#pragma unroll
        for (int i = 0; i < 3; ++i) {
            float4 gg = ((const float4*)g)[i * 256 + tid];
            float4 bb = ((const float4*)b)[i * 256 + tid];
            ushort4 o;
            o.x = f2bf((v[i].x - mean) * rstd * gg.x + bb.x);
            o.y = f2bf((v[i].y - mean) * rstd * gg.y + bb.y);
            o.z = f2bf((v[i].z - mean) * rstd * gg.z + bb.z);
            o.w = f2bf((v[i].w - mean) * rstd * gg.w + bb.w);
            orow[i * 256 + tid] = o;
        }
    } else if (bid < 4096 + 2048) {
        const int n4 = 3 * INNER * DMODEL / 4;
        for (int i = (bid - 4096) * 256 + tid; i < n4; i += 2048 * 256) {
            float4 v = ((const float4*)w_qkv)[i];
            ushort4 o;
            o.x = f2bf(v.x); o.y = f2bf(v.y); o.z = f2bf(v.z); o.w = f2bf(v.w);
            ((ushort4*)wq)[i] = o;
        }
    } else {
        const int n4 = DMODEL * INNER / 4;
        for (int i = (bid - 6144) * 256 + tid; i < n4; i += 512 * 256) {
            float4 v = ((const float4*)w_out)[i];
            ushort4 o;
            o.x = f2bf(v.x); o.y = f2bf(v.y); o.z = f2bf(v.z); o.w = f2bf(v.w);
            ((ushort4*)wo)[i] = o;
        }
    }
}

// ============ GEMM 256x192 8-phase (T2+T3+T4+T5), C = A * B^T ============
// R11: BN 256->192 so grid = (4096/256)x(3072/192) = 256 blocks = EXACT CU
// coverage (was 192/256 CUs = 25% idle). A staging unchanged; B = 192 rows
// = 3 units x 64 rows (1 load each). 7 loads/tile, 14/iter:
//   ph1:(t+1).A1 | ph2-4:(t+2).B0,B1,B2 +VM3 | ph5-6:(t+2).A0,A1 |
//   ph7:(t+3).B0 | ph8:(t+3).B1,B2,A0 +VM5
// VM3: 3 loads issued since t+1 completed (ph1). VM5: 5 since t+2 (ph6).
// MODE 0: C = f32. MODE 2: fused RoPE(Q,K)->Qr/Kr + V->Vt transposed;
// region branch per 16-wide frag (1024/2048 boundaries 16-aligned).

#define VM5 asm volatile("s_waitcnt vmcnt(5)" ::: "memory")
#define VM4 asm volatile("s_waitcnt vmcnt(4)" ::: "memory")
#define VM3 asm volatile("s_waitcnt vmcnt(3)" ::: "memory")
#define VM0 asm volatile("s_waitcnt vmcnt(0)" ::: "memory")
#define LGK8 asm volatile("s_waitcnt lgkmcnt(8)" ::: "memory")
#define NOPS ((void)0)

#define ST_A(d, h, t) do { \
    load_lds16(pA##h##0 + (size_t)(t) * 64, &lds[(d) * 16384 + (h) * 8192 + dq]); \
    load_lds16(pA##h##1 + (size_t)(t) * 64, &lds[(d) * 16384 + (h) * 8192 + dq + 512]); \
  } while (0)
#define ST_B1(d, u, t) \
    load_lds16(pB##u + (size_t)(t) * 64, &lds[32768 + (d) * 12288 + (u) * 4096 + wid * 512])

#define PHASE(d, p, STAGE, PRE, POST) do { \
    bf16x8 afr[2][2]; \
    if ((p) == 0) { \
      _Pragma("unroll") for (int nf = 0; nf < 3; ++nf) { \
        bfr[nf][0] = *(const bf16x8*)&lds[32768 + (d) * 12288 + baseB + nf * 1024 + c0]; \
        bfr[nf][1] = *(const bf16x8*)&lds[32768 + (d) * 12288 + baseB + nf * 1024 + c1]; \
      } \
    } \
    _Pragma("unroll") for (int mfl = 0; mfl < 2; ++mfl) { \
      afr[mfl][0] = *(const bf16x8*)&lds[(d) * 16384 + (p) * 4096 + mfl * 1024 + baseA + c0]; \
      afr[mfl][1] = *(const bf16x8*)&lds[(d) * 16384 + (p) * 4096 + mfl * 1024 + baseA + c1]; \
    } \
    STAGE; \
    PRE; \
    __builtin_amdgcn_s_barrier(); \
    asm volatile("s_waitcnt lgkmcnt(0)" ::: "memory"); \
    __builtin_amdgcn_sched_barrier(0); \
    __builtin_amdgcn_s_setprio(1); \
    _Pragma("unroll") for (int mfl = 0; mfl < 2; ++mfl) \
      _Pragma("unroll") for (int nf = 0; nf < 3; ++nf) { \
        acc[(p) * 2 + mfl][nf] = __builtin_amdgcn_mfma_f32_16x16x32_bf16(afr[mfl][0], bfr[nf][0], acc[(p) * 2 + mfl][nf], 0, 0, 0); \
        acc[(p) * 2 + mfl][nf] = __builtin_amdgcn_mfma_f32_16x16x32_bf16(afr[mfl][1], bfr[nf][1], acc[(p) * 2 + mfl][nf], 0, 0, 0); \
      } \
    __builtin_amdgcn_s_setprio(0); \
    POST; \
    __builtin_amdgcn_s_barrier(); \
  } while (0)

template <int MODE>
__global__ __launch_bounds__(512, 2) void gemm256(const u16* __restrict__ A,
                                                  const u16* __restrict__ B,
                                                  void* __restrict__ C,
                                                  int M, int Nn, int K,
                                                  const float* __restrict__ pe,
                                                  u16* __restrict__ Qr,
                                                  u16* __restrict__ Kr,
                                                  u16* __restrict__ Vt) {
    __shared__ u16 lds[57344];   // A: [2][256][64] @0 (64KB); B: [2][192][64] @32768 (48KB)
    const int tid = threadIdx.x;
    const int lane = tid & 63, wid = tid >> 6;
    const int wm = wid >> 2, wn = wid & 3;
    const int l15 = lane & 15, quad = lane >> 4;
    const int sw = l15 & 7;

    // XCD-aware bijective swizzle (gridDim.x = 256, % 8 == 0)
    int nbx = Nn / 192;
    int cpx = gridDim.x >> 3;
    int wg = (blockIdx.x & 7) * cpx + (blockIdx.x >> 3);
    int m0 = (wg / nbx) << 8, n0 = (wg % nbx) * 192;

    // per-thread ds_read bases (u16 units) and swizzled chunk offsets
    const int baseA = wm * 2048 + l15 * 64;
    const int baseB = wn * 3072 + l15 * 64;   // row = wn*48 + nf*16 + l15
    const int c0 = (quad ^ sw) * 8;
    const int c1 = ((4 + quad) ^ sw) * 8;
    const int dq = wid * 1024;                 // A stage LDS base (j adds 512)

    // stage source pointers, pre-swizzled col
    const u16 *pA00, *pA01, *pA10, *pA11, *pB0, *pB1, *pB2;
    {
        int scol = ((lane & 7) ^ (lane >> 3)) * 8;
#define MKSRCA(h, j, PA) { \
        int ell = (h) * 128 + (wid * 2 + (j)) * 8 + (lane >> 3); \
        int g = ell >> 6, wmh = (ell >> 5) & 1, r = ell & 31; \
        PA = A + (size_t)(m0 + wmh * 128 + g * 32 + r) * K + scol; }
#define MKSRCB(u, PB) { \
        int ell = (u) * 64 + wid * 8 + (lane >> 3); \
        PB = B + (size_t)(n0 + ell) * K + scol; }
        MKSRCA(0, 0, pA00) MKSRCA(0, 1, pA01)
        MKSRCA(1, 0, pA10) MKSRCA(1, 1, pA11)
        MKSRCB(0, pB0) MKSRCB(1, pB1) MKSRCB(2, pB2)
#undef MKSRCA
#undef MKSRCB
    }

    f32x4 acc[8][3];
    f32x4 zero4 = {0.f, 0.f, 0.f, 0.f};
#pragma unroll
    for (int i = 0; i < 8; ++i)
#pragma unroll
        for (int j = 0; j < 3; ++j) acc[i][j] = zero4;
    bf16x8 bfr[3][2];

    // prologue: tile0 full (7 loads) -> buf0; tile1 B0,B1,B2,A0 (5) -> buf1
    ST_B1(0, 0, 0); ST_B1(0, 1, 0); ST_B1(0, 2, 0); ST_A(0, 0, 0); ST_A(0, 1, 0);
    ST_B1(1, 0, 1); ST_B1(1, 1, 1); ST_B1(1, 2, 1); ST_A(1, 0, 1);
    VM5;                                   // tile0's 7 landed; 5 in flight
    __builtin_amdgcn_s_barrier();

    const int NIT = (K >> 7) - 1;          // T/2 - 1 iterations
    for (int i = 0; i < NIT; ++i) {
        int t = 2 * i;
        PHASE(0, 0, ST_A(1, 1, t + 1), LGK8, NOPS);
        PHASE(0, 1, ST_B1(0, 0, t + 2), NOPS, NOPS);
        PHASE(0, 2, ST_B1(0, 1, t + 2), NOPS, NOPS);
        PHASE(0, 3, ST_B1(0, 2, t + 2), NOPS, VM3);
        PHASE(1, 0, ST_A(0, 0, t + 2), LGK8, NOPS);
        PHASE(1, 1, ST_A(0, 1, t + 2), NOPS, NOPS);
        PHASE(1, 2, ST_B1(1, 0, t + 3), NOPS, NOPS);
        PHASE(1, 3, { ST_B1(1, 1, t + 3); ST_B1(1, 2, t + 3); ST_A(1, 0, t + 3); }, NOPS, VM5);
    }
    {   // epilogue: tiles T-2 (buf0), T-1 (buf1); only (T-1).A1 left to stage
        int T = K >> 6;
        PHASE(0, 0, ST_A(1, 1, T - 1), LGK8, NOPS);
        PHASE(0, 1, NOPS, NOPS, NOPS);
        PHASE(0, 2, NOPS, NOPS, NOPS);
        PHASE(0, 3, NOPS, NOPS, VM0);
        PHASE(1, 0, NOPS, LGK8, NOPS);
        PHASE(1, 1, NOPS, NOPS, NOPS);
        PHASE(1, 2, NOPS, NOPS, NOPS);
        PHASE(1, 3, NOPS, NOPS, NOPS);
    }

    if (MODE == 0) {
        // C write: rr = m0+wm*128+mf*16+quad*4+r ; cc = n0+wn*48+nf*16+l15
#pragma unroll
        for (int mf = 0; mf < 8; ++mf)
#pragma unroll
            for (int nf = 0; nf < 3; ++nf)
#pragma unroll
                for (int r = 0; r < 4; ++r) {
                    int rr = m0 + wm * 128 + mf * 16 + quad * 4 + r;
                    int cc = n0 + wn * 48 + nf * 16 + l15;
                    ((float*)C)[(size_t)rr * Nn + cc] = acc[mf][nf][r];
                }
    } else {
#pragma unroll
        for (int nf = 0; nf < 3; ++nf) {
            int cc = n0 + wn * 48 + nf * 16 + l15;
            if (cc < 2048) {
                // Q or K frag: RoPE (col pairs 2i,2i+1 = lane pairs l15^1)
                const int isQ = (cc < 1024);
                const float scl = isQ ? SCALE_LOG2E : 1.f;
                u16* dst = isQ ? Qr : Kr;
                int hh = (cc & 1023) >> 6;
                int ii = (cc & 63) >> 1;
                int jj = cc & 1;
#pragma unroll
                for (int mf = 0; mf < 8; ++mf)
#pragma unroll
                    for (int r = 0; r < 4; ++r) {
                        int rr = m0 + wm * 128 + mf * 16 + quad * 4 + r;
                        float v = acc[mf][nf][r];
                        float vp = __shfl_xor(v, 1);
                        float v0 = jj ? vp : v;
                        float v1 = jj ? v : vp;
                        const float* pw = pe + (size_t)rr * 128 + ii * 4 + jj * 2;
                        float ov = (pw[0] * v0 + pw[1] * v1) * scl;
                        dst[((size_t)hh * N_TOK + rr) * 64 + (cc & 63)] = f2bf(ov);
                    }
            } else {
                // V frag: write transposed Vt[h][d][n] — ushort4 of 4 rows
                int hh = (cc - 2048) >> 6, dd = cc & 63;
#pragma unroll
                for (int mf = 0; mf < 8; ++mf) {
                    int rr = m0 + wm * 128 + mf * 16 + quad * 4;
                    ushort4 o4;
                    o4.x = f2bf(acc[mf][nf][0]); o4.y = f2bf(acc[mf][nf][1]);
                    o4.z = f2bf(acc[mf][nf][2]); o4.w = f2bf(acc[mf][nf][3]);
                    *(ushort4*)&Vt[((size_t)hh * 64 + dd) * N_TOK + rr] = o4;
                }
            }
        }
    }
}

// ---------------- Flash attention: R9 (unchanged control) -----------------
// 4 waves x 32 q-rows, QBLK=128, 2 blocks/CU; 3x16KB K/V rotation, split
// lgkm(8)/lgkm(0) waits, counted vmcnt(4), in-register P exchange.

#define FA_STAGE3(dst, kt) do { \
    load_lds16(&Kh[(size_t)((kt) + krow) * DHEAD + csw], &lds_all[(dst) + kbase]); \
    load_lds16(&Kh[(size_t)((kt) + krow + 8) * DHEAD + csw], &lds_all[(dst) + kbase + 512]); \
    load_lds16(&Vh[(size_t)krow * N_TOK + (kt) + csw], &lds_all[(dst) + 4096 + kbase]); \
    load_lds16(&Vh[(size_t)(krow + 8) * N_TOK + (kt) + csw], &lds_all[(dst) + 4096 + kbase + 512]); \
  } while (0)

__global__ __launch_bounds__(256, 2) void flash_attn(const u16* __restrict__ Q,
                                                     const u16* __restrict__ K,
                                                     const u16* __restrict__ Vt,
                                                     u16* __restrict__ O) {
    __shared__ u16 lds_all[24576];           // 48 KB: 3 x 16KB K/V rotation
    int tid = threadIdx.x, lane = tid & 63, wid = tid >> 6;
    int l15 = lane & 15, quad = lane >> 4;
    int sw = l15 & 7;
    int h = blockIdx.y;
    int q0 = blockIdx.x * 128 + wid * 32;
    const u16* Qh = Q + (size_t)h * N_TOK * DHEAD;
    const u16* Kh = K + (size_t)h * N_TOK * DHEAD;
    const u16* Vh = Vt + (size_t)h * DHEAD * N_TOK;

    f32x4 zero4 = {0.f, 0.f, 0.f, 0.f};
    bf16x8 ones;
#pragma unroll
    for (int i = 0; i < 8; ++i) ones[i] = (short)0x3F80;  // bf16 1.0

    // Q fragments (B operand): B[n=q=l15][k=dhead]
    bf16x8 aq[2][2];
#pragma unroll
    for (int mtQ = 0; mtQ < 2; ++mtQ)
#pragma unroll
        for (int kc = 0; kc < 2; ++kc)
            aq[mtQ][kc] = *(const bf16x8*)&Qh[(size_t)(q0 + mtQ * 16 + l15) * DHEAD + kc * 32 + quad * 8];

    f32x4 o[2][4], lacc[2];
#pragma unroll
    for (int mtQ = 0; mtQ < 2; ++mtQ) {
#pragma unroll
        for (int dt = 0; dt < 4; ++dt) o[mtQ][dt] = zero4;
        lacc[mtQ] = zero4;
    }

    // staging: wave stages K rows [wid*16, wid*16+16) and V rows same range
    int rowoff = lane >> 3;                      // 0..7
    int krow = wid * 16 + rowoff;                // 0..63 (with +8 variant)
    int kbase = wid * 1024;                      // u16: wid*16 rows * 64
    int csw = ((lane & 7) ^ rowoff) * 8;         // swizzled source column (u16)

    // prologue: tiles 0,1 -> bufs 0,1; wait tile0 (tile1's 4 loads in flight)
    FA_STAGE3(0, 0);
    FA_STAGE3(8192, 64);
    VM4;
    __builtin_amdgcn_s_barrier();
    __builtin_amdgcn_sched_barrier(0);

    int cur = 0;
    for (int t = 0; t < 64; ++t) {
        int stg = cur + 16384; if (stg >= 24576) stg -= 24576;  // (t+2)%3
        bf16x8 bk[4][2], av[4][2];
#pragma unroll
        for (int tt = 0; tt < 4; ++tt)
#pragma unroll
            for (int kc = 0; kc < 2; ++kc)
                bk[tt][kc] = *(const bf16x8*)&lds_all[cur + (tt * 16 + l15) * 64 + (((kc * 4 + quad) ^ sw) * 8)];
        __builtin_amdgcn_sched_barrier(0);
#pragma unroll
        for (int tt = 0; tt < 4; ++tt)
#pragma unroll
            for (int kc = 0; kc < 2; ++kc)
                av[tt][kc] = *(const bf16x8*)&lds_all[cur + 4096 + (tt * 16 + l15) * 64 + (((kc * 4 + quad) ^ sw) * 8)];
        __builtin_amdgcn_sched_barrier(0);
        if (t < 62) FA_STAGE3(stg, (t + 2) * 64);
        asm volatile("s_waitcnt lgkmcnt(8)" ::: "memory");   // bk ready; av in flight
        __builtin_amdgcn_sched_barrier(0);

        bf16x8 bp[2][2];
#pragma unroll
        for (int mtQ = 0; mtQ < 2; ++mtQ) {
            f32x4 s[4];
            __builtin_amdgcn_s_setprio(1);
#pragma unroll
            for (int ntK = 0; ntK < 4; ++ntK) {
                f32x4 t0 = __builtin_amdgcn_mfma_f32_16x16x32_bf16(bk[ntK][0], aq[mtQ][0], zero4, 0, 0, 0);
                s[ntK] = __builtin_amdgcn_mfma_f32_16x16x32_bf16(bk[ntK][1], aq[mtQ][1], t0, 0, 0, 0);
            }
            __builtin_amdgcn_s_setprio(0);
            unsigned pw[4][2];
#pragma unroll
            for (int ntK = 0; ntK < 4; ++ntK) {
                pw[ntK][0] = pk2bf(__builtin_amdgcn_exp2f(s[ntK][0]), __builtin_amdgcn_exp2f(s[ntK][1]));
                pw[ntK][1] = pk2bf(__builtin_amdgcn_exp2f(s[ntK][2]), __builtin_amdgcn_exp2f(s[ntK][3]));
            }
            bp[mtQ][0] = build_bp(pw[0][0], pw[0][1], pw[1][0], pw[1][1]);
            bp[mtQ][1] = build_bp(pw[2][0], pw[2][1], pw[3][0], pw[3][1]);
        }

        asm volatile("s_waitcnt lgkmcnt(0)" ::: "memory");   // av ready
        __builtin_amdgcn_sched_barrier(0);
        __builtin_amdgcn_s_setprio(1);
#pragma unroll
        for (int mtQ = 0; mtQ < 2; ++mtQ) {
            lacc[mtQ] = __builtin_amdgcn_mfma_f32_16x16x32_bf16(ones, bp[mtQ][0], lacc[mtQ], 0, 0, 0);
            lacc[mtQ] = __builtin_amdgcn_mfma_f32_16x16x32_bf16(ones, bp[mtQ][1], lacc[mtQ], 0, 0, 0);
#pragma unroll
            for (int dt = 0; dt < 4; ++dt) {
                o[mtQ][dt] = __builtin_amdgcn_mfma_f32_16x16x32_bf16(av[dt][0], bp[mtQ][0], o[mtQ][dt], 0, 0, 0);
                o[mtQ][dt] = __builtin_amdgcn_mfma_f32_16x16x32_bf16(av[dt][1], bp[mtQ][1], o[mtQ][dt], 0, 0, 0);
            }
        }
        __builtin_amdgcn_s_setprio(0);

        if (t < 62) { VM4; } else if (t == 62) { VM0; }
        __builtin_amdgcn_s_barrier();
        __builtin_amdgcn_sched_barrier(0);
        cur += 8192; if (cur >= 24576) cur -= 24576;
    }

    // epilogue: transpose O^T -> O via per-wave LDS scratch, then coalesced write
    __syncthreads();
    u16* scratch = lds_all + wid * 2048;     // [q 32][d 64] per wave (4 KB)
#pragma unroll
    for (int mtQ = 0; mtQ < 2; ++mtQ) {
        float rl = 1.f / lacc[mtQ][0];
#pragma unroll
        for (int dt = 0; dt < 4; ++dt) {
            uint2 ov;
            ov.x = pk2bf(o[mtQ][dt][0] * rl, o[mtQ][dt][1] * rl);
            ov.y = pk2bf(o[mtQ][dt][2] * rl, o[mtQ][dt][3] * rl);
            *(uint2*)&scratch[(mtQ * 16 + l15) * 64 + dt * 16 + quad * 4] = ov;
        }
    }
    __syncthreads();
#pragma unroll
    for (int p = 0; p < 4; ++p) {
        int q_local = p * 8 + (lane >> 3);
        int dcol = (lane & 7) * 8;
        bf16x8 v = *(const bf16x8*)&scratch[q_local * 64 + dcol];
        *(bf16x8*)&O[(size_t)(q0 + q_local) * INNER + h * 64 + dcol] = v;
    }
}

extern "C" void kernel_launch(void* const* d_in, const int* in_sizes, int n_in,
                              void* d_out, int out_size, void* d_ws, size_t ws_size,
                              hipStream_t stream) {
    const float* x     = (const float*)d_in[0];
    const float* pe    = (const float*)d_in[1];
    const float* w_qkv = (const float*)d_in[2];
    const float* w_out = (const float*)d_in[3];
    const float* ln_g  = (const float*)d_in[4];
    const float* ln_b  = (const float*)d_in[5];
    float* out = (float*)d_out;

    char* ws = (char*)d_ws;
    u16* xn  = (u16*)ws;  ws += (size_t)N_TOK * DMODEL * 2;
    u16* wq  = (u16*)ws;  ws += (size_t)3 * INNER * DMODEL * 2;
    u16* wo  = (u16*)ws;  ws += (size_t)DMODEL * INNER * 2;
    u16* Qr  = (u16*)ws;  ws += (size_t)NH * N_TOK * DHEAD * 2;
    u16* Kr  = (u16*)ws;  ws += (size_t)NH * N_TOK * DHEAD * 2;
    u16* Vt  = (u16*)ws;  ws += (size_t)NH * DHEAD * N_TOK * 2;
    u16* Ob  = (u16*)ws;  ws += (size_t)N_TOK * INNER * 2;

    prep<<<4096 + 2048 + 512, 256, 0, stream>>>(x, ln_g, ln_b, xn, w_qkv, wq, w_out, wo);
    gemm256<2><<<dim3((N_TOK / 256) * (DMODEL / 192)), 512, 0, stream>>>(
        xn, wq, nullptr, N_TOK, DMODEL, DMODEL, pe, Qr, Kr, Vt);
    flash_attn<<<dim3(N_TOK / 128, NH), 256, 0, stream>>>(Qr, Kr, Vt, Ob);
    gemm256<0><<<dim3((N_TOK / 256) * (DMODEL / 192)), 512, 0, stream>>>(
        Ob, wo, out, N_TOK, DMODEL, INNER, nullptr, nullptr, nullptr, nullptr);
}

// Round 12
// 331.060 us; speedup vs baseline: 1.0791x; 1.0538x over previous
//
#include <hip/hip_runtime.h>
#include <hip/hip_bf16.h>

typedef unsigned short u16;
typedef __attribute__((ext_vector_type(8))) short bf16x8;
typedef __attribute__((ext_vector_type(4))) float f32x4;

#define N_TOK 4096
#define DMODEL 3072
#define NH 16
#define DHEAD 64
#define INNER 1024
#define SCALE_LOG2E 0.18033688011112042f  /* (1/8) * log2(e) */

__device__ __forceinline__ u16 f2bf(float f) {
    union { float f; unsigned u; } un; un.f = f;
    unsigned r = un.u + 0x7fffu + ((un.u >> 16) & 1u);
    return (u16)(r >> 16);
}
__device__ __forceinline__ float bf2f(u16 u) {
    union { unsigned u; float f; } x; x.u = ((unsigned)u) << 16; return x.f;
}
// pack two f32 -> two bf16 (round-half-up) in 3 VALU ops; a -> low 16
__device__ __forceinline__ unsigned pk2bf(float a, float b) {
    union { float f; unsigned u; } ua, ub; ua.f = a; ub.f = b;
    return __builtin_amdgcn_perm(ub.u + 0x8000u, ua.u + 0x8000u, 0x07060302u);
}
__device__ __forceinline__ void load_lds16(const u16* g, u16* l) {
    __builtin_amdgcn_global_load_lds(
        (const __attribute__((address_space(1))) unsigned int*)g,
        (__attribute__((address_space(3))) unsigned int*)l, 16, 0, 0);
}

// Build PV B-operand in-register from packed exp2(S^T) words.
// Output: lane (l15,quad) holds keys [8*quad, 8*quad+8) for col q=l15.
__device__ __forceinline__ bf16x8 build_bp(unsigned u0, unsigned u1,
                                           unsigned w0, unsigned w1) {
    auto a = __builtin_amdgcn_permlane32_swap(u0, w0, false, false);
    auto b = __builtin_amdgcn_permlane16_swap(a[0], a[1], false, false);
    auto c = __builtin_amdgcn_permlane32_swap(u1, w1, false, false);
    auto d = __builtin_amdgcn_permlane16_swap(c[0], c[1], false, false);
    union { unsigned w[4]; bf16x8 v; } r;
    r.w[0] = b[0]; r.w[1] = d[0]; r.w[2] = b[1]; r.w[3] = d[1];
    return r.v;
}

// ------- Fused prep: LN rows (blocks 0..4095), wq cvt (4096..6143), --------
// ------- wo cvt (6144..6655). --------
__global__ __launch_bounds__(256) void prep(const float* __restrict__ x,
                                            const float* __restrict__ g,
                                            const float* __restrict__ b,
                                            u16* __restrict__ xn,
                                            const float* __restrict__ w_qkv,
                                            u16* __restrict__ wq,
                                            const float* __restrict__ w_out,
                                            u16* __restrict__ wo) {
    int bid = blockIdx.x;
    int tid = threadIdx.x;
    if (bid < 4096) {
        int row = bid;
        const float4* xr = (const float4*)(x + (size_t)row * DMODEL);
        float4 v[3];
        float s = 0.f, ss = 0.f;
#pragma unroll
        for (int i = 0; i < 3; ++i) {
            v[i] = xr[i * 256 + tid];
            s  += v[i].x + v[i].y + v[i].z + v[i].w;
            ss += v[i].x * v[i].x + v[i].y * v[i].y + v[i].z * v[i].z + v[i].w * v[i].w;
        }
#pragma unroll
        for (int off = 32; off; off >>= 1) {
            s  += __shfl_xor(s, off);
            ss += __shfl_xor(ss, off);
        }
        __shared__ float red[8];
        int wid = tid >> 6, lane = tid & 63;
        if (lane == 0) { red[wid] = s; red[wid + 4] = ss; }
        __syncthreads();
        s  = red[0] + red[1] + red[2] + red[3];
        ss = red[4] + red[5] + red[6] + red[7];
        float mean = s * (1.f / DMODEL);
        float var  = ss * (1.f / DMODEL) - mean * mean;
        float rstd = rsqrtf(var + 1e-5f);
        ushort4* orow = (ushort4*)(xn + (size_t)row * DMODEL);
#pragma unroll
        for (int i = 0; i < 3; ++i) {
            float4 gg = ((const float4*)g)[i * 256 + tid];
            float4 bb = ((const float4*)b)[i * 256 + tid];
            ushort4 o;
            o.x = f2bf((v[i].x - mean) * rstd * gg.x + bb.x);
            o.y = f2bf((v[i].y - mean) * rstd * gg.y + bb.y);
            o.z = f2bf((v[i].z - mean) * rstd * gg.z + bb.z);
            o.w = f2bf((v[i].w - mean) * rstd * gg.w + bb.w);
            orow[i * 256 + tid] = o;
        }
    } else if (bid < 4096 + 2048) {
        const int n4 = 3 * INNER * DMODEL / 4;
        for (int i = (bid - 4096) * 256 + tid; i < n4; i += 2048 * 256) {
            float4 v = ((const float4*)w_qkv)[i];
            ushort4 o;
            o.x = f2bf(v.x); o.y = f2bf(v.y); o.z = f2bf(v.z); o.w = f2bf(v.w);
            ((ushort4*)wq)[i] = o;
        }
    } else {
        const int n4 = DMODEL * INNER / 4;
        for (int i = (bid - 6144) * 256 + tid; i < n4; i += 512 * 256) {
            float4 v = ((const float4*)w_out)[i];
            ushort4 o;
            o.x = f2bf(v.x); o.y = f2bf(v.y); o.z = f2bf(v.z); o.w = f2bf(v.w);
            ((ushort4*)wo)[i] = o;
        }
    }
}

// ============ GEMM 256x192 8-phase (T2+T3+T4+T5), C = A * B^T ============
// (R11 geometry — verified; control this round)

#define VM5 asm volatile("s_waitcnt vmcnt(5)" ::: "memory")
#define VM4 asm volatile("s_waitcnt vmcnt(4)" ::: "memory")
#define VM3 asm volatile("s_waitcnt vmcnt(3)" ::: "memory")
#define VM0 asm volatile("s_waitcnt vmcnt(0)" ::: "memory")
#define LGK8 asm volatile("s_waitcnt lgkmcnt(8)" ::: "memory")
#define NOPS ((void)0)

#define ST_A(d, h, t) do { \
    load_lds16(pA##h##0 + (size_t)(t) * 64, &lds[(d) * 16384 + (h) * 8192 + dq]); \
    load_lds16(pA##h##1 + (size_t)(t) * 64, &lds[(d) * 16384 + (h) * 8192 + dq + 512]); \
  } while (0)
#define ST_B1(d, u, t) \
    load_lds16(pB##u + (size_t)(t) * 64, &lds[32768 + (d) * 12288 + (u) * 4096 + wid * 512])

#define PHASE(d, p, STAGE, PRE, POST) do { \
    bf16x8 afr[2][2]; \
    if ((p) == 0) { \
      _Pragma("unroll") for (int nf = 0; nf < 3; ++nf) { \
        bfr[nf][0] = *(const bf16x8*)&lds[32768 + (d) * 12288 + baseB + nf * 1024 + c0]; \
        bfr[nf][1] = *(const bf16x8*)&lds[32768 + (d) * 12288 + baseB + nf * 1024 + c1]; \
      } \
    } \
    _Pragma("unroll") for (int mfl = 0; mfl < 2; ++mfl) { \
      afr[mfl][0] = *(const bf16x8*)&lds[(d) * 16384 + (p) * 4096 + mfl * 1024 + baseA + c0]; \
      afr[mfl][1] = *(const bf16x8*)&lds[(d) * 16384 + (p) * 4096 + mfl * 1024 + baseA + c1]; \
    } \
    STAGE; \
    PRE; \
    __builtin_amdgcn_s_barrier(); \
    asm volatile("s_waitcnt lgkmcnt(0)" ::: "memory"); \
    __builtin_amdgcn_sched_barrier(0); \
    __builtin_amdgcn_s_setprio(1); \
    _Pragma("unroll") for (int mfl = 0; mfl < 2; ++mfl) \
      _Pragma("unroll") for (int nf = 0; nf < 3; ++nf) { \
        acc[(p) * 2 + mfl][nf] = __builtin_amdgcn_mfma_f32_16x16x32_bf16(afr[mfl][0], bfr[nf][0], acc[(p) * 2 + mfl][nf], 0, 0, 0); \
        acc[(p) * 2 + mfl][nf] = __builtin_amdgcn_mfma_f32_16x16x32_bf16(afr[mfl][1], bfr[nf][1], acc[(p) * 2 + mfl][nf], 0, 0, 0); \
      } \
    __builtin_amdgcn_s_setprio(0); \
    POST; \
    __builtin_amdgcn_s_barrier(); \
  } while (0)

template <int MODE>
__global__ __launch_bounds__(512, 2) void gemm256(const u16* __restrict__ A,
                                                  const u16* __restrict__ B,
                                                  void* __restrict__ C,
                                                  int M, int Nn, int K,
                                                  const float* __restrict__ pe,
                                                  u16* __restrict__ Qr,
                                                  u16* __restrict__ Kr,
                                                  u16* __restrict__ Vt) {
    __shared__ u16 lds[57344];   // A: [2][256][64] @0 (64KB); B: [2][192][64] @32768 (48KB)
    const int tid = threadIdx.x;
    const int lane = tid & 63, wid = tid >> 6;
    const int wm = wid >> 2, wn = wid & 3;
    const int l15 = lane & 15, quad = lane >> 4;
    const int sw = l15 & 7;

    // XCD-aware bijective swizzle (gridDim.x = 256, % 8 == 0)
    int nbx = Nn / 192;
    int cpx = gridDim.x >> 3;
    int wg = (blockIdx.x & 7) * cpx + (blockIdx.x >> 3);
    int m0 = (wg / nbx) << 8, n0 = (wg % nbx) * 192;

    // per-thread ds_read bases (u16 units) and swizzled chunk offsets
    const int baseA = wm * 2048 + l15 * 64;
    const int baseB = wn * 3072 + l15 * 64;   // row = wn*48 + nf*16 + l15
    const int c0 = (quad ^ sw) * 8;
    const int c1 = ((4 + quad) ^ sw) * 8;
    const int dq = wid * 1024;                 // A stage LDS base (j adds 512)

    // stage source pointers, pre-swizzled col
    const u16 *pA00, *pA01, *pA10, *pA11, *pB0, *pB1, *pB2;
    {
        int scol = ((lane & 7) ^ (lane >> 3)) * 8;
#define MKSRCA(h, j, PA) { \
        int ell = (h) * 128 + (wid * 2 + (j)) * 8 + (lane >> 3); \
        int g = ell >> 6, wmh = (ell >> 5) & 1, r = ell & 31; \
        PA = A + (size_t)(m0 + wmh * 128 + g * 32 + r) * K + scol; }
#define MKSRCB(u, PB) { \
        int ell = (u) * 64 + wid * 8 + (lane >> 3); \
        PB = B + (size_t)(n0 + ell) * K + scol; }
        MKSRCA(0, 0, pA00) MKSRCA(0, 1, pA01)
        MKSRCA(1, 0, pA10) MKSRCA(1, 1, pA11)
        MKSRCB(0, pB0) MKSRCB(1, pB1) MKSRCB(2, pB2)
#undef MKSRCA
#undef MKSRCB
    }

    f32x4 acc[8][3];
    f32x4 zero4 = {0.f, 0.f, 0.f, 0.f};
#pragma unroll
    for (int i = 0; i < 8; ++i)
#pragma unroll
        for (int j = 0; j < 3; ++j) acc[i][j] = zero4;
    bf16x8 bfr[3][2];

    // prologue: tile0 full (7 loads) -> buf0; tile1 B0,B1,B2,A0 (5) -> buf1
    ST_B1(0, 0, 0); ST_B1(0, 1, 0); ST_B1(0, 2, 0); ST_A(0, 0, 0); ST_A(0, 1, 0);
    ST_B1(1, 0, 1); ST_B1(1, 1, 1); ST_B1(1, 2, 1); ST_A(1, 0, 1);
    VM5;                                   // tile0's 7 landed; 5 in flight
    __builtin_amdgcn_s_barrier();

    const int NIT = (K >> 7) - 1;          // T/2 - 1 iterations
    for (int i = 0; i < NIT; ++i) {
        int t = 2 * i;
        PHASE(0, 0, ST_A(1, 1, t + 1), LGK8, NOPS);
        PHASE(0, 1, ST_B1(0, 0, t + 2), NOPS, NOPS);
        PHASE(0, 2, ST_B1(0, 1, t + 2), NOPS, NOPS);
        PHASE(0, 3, ST_B1(0, 2, t + 2), NOPS, VM3);
        PHASE(1, 0, ST_A(0, 0, t + 2), LGK8, NOPS);
        PHASE(1, 1, ST_A(0, 1, t + 2), NOPS, NOPS);
        PHASE(1, 2, ST_B1(1, 0, t + 3), NOPS, NOPS);
        PHASE(1, 3, { ST_B1(1, 1, t + 3); ST_B1(1, 2, t + 3); ST_A(1, 0, t + 3); }, NOPS, VM5);
    }
    {   // epilogue: tiles T-2 (buf0), T-1 (buf1); only (T-1).A1 left to stage
        int T = K >> 6;
        PHASE(0, 0, ST_A(1, 1, T - 1), LGK8, NOPS);
        PHASE(0, 1, NOPS, NOPS, NOPS);
        PHASE(0, 2, NOPS, NOPS, NOPS);
        PHASE(0, 3, NOPS, NOPS, VM0);
        PHASE(1, 0, NOPS, LGK8, NOPS);
        PHASE(1, 1, NOPS, NOPS, NOPS);
        PHASE(1, 2, NOPS, NOPS, NOPS);
        PHASE(1, 3, NOPS, NOPS, NOPS);
    }

    if (MODE == 0) {
        // C write: rr = m0+wm*128+mf*16+quad*4+r ; cc = n0+wn*48+nf*16+l15
#pragma unroll
        for (int mf = 0; mf < 8; ++mf)
#pragma unroll
            for (int nf = 0; nf < 3; ++nf)
#pragma unroll
                for (int r = 0; r < 4; ++r) {
                    int rr = m0 + wm * 128 + mf * 16 + quad * 4 + r;
                    int cc = n0 + wn * 48 + nf * 16 + l15;
                    ((float*)C)[(size_t)rr * Nn + cc] = acc[mf][nf][r];
                }
    } else {
#pragma unroll
        for (int nf = 0; nf < 3; ++nf) {
            int cc = n0 + wn * 48 + nf * 16 + l15;
            if (cc < 2048) {
                // Q or K frag: RoPE (col pairs 2i,2i+1 = lane pairs l15^1)
                const int isQ = (cc < 1024);
                const float scl = isQ ? SCALE_LOG2E : 1.f;
                u16* dst = isQ ? Qr : Kr;
                int hh = (cc & 1023) >> 6;
                int ii = (cc & 63) >> 1;
                int jj = cc & 1;
#pragma unroll
                for (int mf = 0; mf < 8; ++mf)
#pragma unroll
                    for (int r = 0; r < 4; ++r) {
                        int rr = m0 + wm * 128 + mf * 16 + quad * 4 + r;
                        float v = acc[mf][nf][r];
                        float vp = __shfl_xor(v, 1);
                        float v0 = jj ? vp : v;
                        float v1 = jj ? v : vp;
                        const float* pw = pe + (size_t)rr * 128 + ii * 4 + jj * 2;
                        float ov = (pw[0] * v0 + pw[1] * v1) * scl;
                        dst[((size_t)hh * N_TOK + rr) * 64 + (cc & 63)] = f2bf(ov);
                    }
            } else {
                // V frag: write transposed Vt[h][d][n] — ushort4 of 4 rows
                int hh = (cc - 2048) >> 6, dd = cc & 63;
#pragma unroll
                for (int mf = 0; mf < 8; ++mf) {
                    int rr = m0 + wm * 128 + mf * 16 + quad * 4;
                    ushort4 o4;
                    o4.x = f2bf(acc[mf][nf][0]); o4.y = f2bf(acc[mf][nf][1]);
                    o4.z = f2bf(acc[mf][nf][2]); o4.w = f2bf(acc[mf][nf][3]);
                    *(ushort4*)&Vt[((size_t)hh * 64 + dd) * N_TOK + rr] = o4;
                }
            }
        }
    }
}

// ------ Flash attention R12: T15 two-tile pipeline + cvt_pk softmax -------
// 4 waves x 32 q-rows, QBLK=128, 2 blocks/CU; 3x16KB K/V rotation.
// R11 counters: VALU 49% + LDS ~43% + MFMA = ~100% — zero in-wave overlap
// (exp2 reads s immediately after the QK MFMAs that produce it -> stall).
// R12: defer softmax+PV of tile t-1 to overlap QK(t)'s MFMA drain (T15,
// +7-11% measured on attn). s/av double-buffered in regs via explicit
// 2-half unroll (rule #20: static names, no runtime idx). cvt_pk asm
// replaces 3-op pk2bf (T12). O,l are pure sums (fixed-bias) — deferral
// is numerically exact up to f32 add order.

#define FA_STAGE3(dst, kt) do { \
    load_lds16(&Kh[(size_t)((kt) + krow) * DHEAD + csw], &lds_all[(dst) + kbase]); \
    load_lds16(&Kh[(size_t)((kt) + krow + 8) * DHEAD + csw], &lds_all[(dst) + kbase + 512]); \
    load_lds16(&Vh[(size_t)krow * N_TOK + (kt) + csw], &lds_all[(dst) + 4096 + kbase]); \
    load_lds16(&Vh[(size_t)(krow + 8) * N_TOK + (kt) + csw], &lds_all[(dst) + 4096 + kbase + 512]); \
  } while (0)

#define FA_READ(CUR, AV) do { \
    _Pragma("unroll") for (int tt = 0; tt < 4; ++tt) \
      _Pragma("unroll") for (int kc = 0; kc < 2; ++kc) \
        bk[tt][kc] = *(const bf16x8*)&lds_all[(CUR) + (tt * 16 + l15) * 64 + (((kc * 4 + quad) ^ sw) * 8)]; \
    __builtin_amdgcn_sched_barrier(0); \
    _Pragma("unroll") for (int tt = 0; tt < 4; ++tt) \
      _Pragma("unroll") for (int kc = 0; kc < 2; ++kc) \
        AV[tt][kc] = *(const bf16x8*)&lds_all[(CUR) + 4096 + (tt * 16 + l15) * 64 + (((kc * 4 + quad) ^ sw) * 8)]; \
    __builtin_amdgcn_sched_barrier(0); \
  } while (0)

#define LGK8F do { asm volatile("s_waitcnt lgkmcnt(8)" ::: "memory"); __builtin_amdgcn_sched_barrier(0); } while (0)
#define LGK0F do { asm volatile("s_waitcnt lgkmcnt(0)" ::: "memory"); __builtin_amdgcn_sched_barrier(0); } while (0)

#define FA_QK(S) do { \
    __builtin_amdgcn_s_setprio(1); \
    _Pragma("unroll") for (int mtQ = 0; mtQ < 2; ++mtQ) \
      _Pragma("unroll") for (int ntK = 0; ntK < 4; ++ntK) { \
        f32x4 t0 = __builtin_amdgcn_mfma_f32_16x16x32_bf16(bk[ntK][0], aq[mtQ][0], zero4, 0, 0, 0); \
        S[mtQ][ntK] = __builtin_amdgcn_mfma_f32_16x16x32_bf16(bk[ntK][1], aq[mtQ][1], t0, 0, 0, 0); \
      } \
    __builtin_amdgcn_s_setprio(0); \
  } while (0)

#define FA_SMPV(SP, AVP) do { \
    _Pragma("unroll") for (int mtQ = 0; mtQ < 2; ++mtQ) { \
      unsigned pw[4][2]; \
      _Pragma("unroll") for (int ntK = 0; ntK < 4; ++ntK) { \
        float e0 = __builtin_amdgcn_exp2f(SP[mtQ][ntK][0]); \
        float e1 = __builtin_amdgcn_exp2f(SP[mtQ][ntK][1]); \
        float e2 = __builtin_amdgcn_exp2f(SP[mtQ][ntK][2]); \
        float e3 = __builtin_amdgcn_exp2f(SP[mtQ][ntK][3]); \
        asm("v_cvt_pk_bf16_f32 %0, %1, %2" : "=v"(pw[ntK][0]) : "v"(e0), "v"(e1)); \
        asm("v_cvt_pk_bf16_f32 %0, %1, %2" : "=v"(pw[ntK][1]) : "v"(e2), "v"(e3)); \
      } \
      bf16x8 bp0 = build_bp(pw[0][0], pw[0][1], pw[1][0], pw[1][1]); \
      bf16x8 bp1 = build_bp(pw[2][0], pw[2][1], pw[3][0], pw[3][1]); \
      __builtin_amdgcn_s_setprio(1); \
      lacc[mtQ] = __builtin_amdgcn_mfma_f32_16x16x32_bf16(ones, bp0, lacc[mtQ], 0, 0, 0); \
      lacc[mtQ] = __builtin_amdgcn_mfma_f32_16x16x32_bf16(ones, bp1, lacc[mtQ], 0, 0, 0); \
      _Pragma("unroll") for (int dt = 0; dt < 4; ++dt) { \
        o[mtQ][dt] = __builtin_amdgcn_mfma_f32_16x16x32_bf16(AVP[dt][0], bp0, o[mtQ][dt], 0, 0, 0); \
        o[mtQ][dt] = __builtin_amdgcn_mfma_f32_16x16x32_bf16(AVP[dt][1], bp1, o[mtQ][dt], 0, 0, 0); \
      } \
      __builtin_amdgcn_s_setprio(0); \
    } \
  } while (0)

__global__ __launch_bounds__(256, 2) void flash_attn(const u16* __restrict__ Q,
                                                     const u16* __restrict__ K,
                                                     const u16* __restrict__ Vt,
                                                     u16* __restrict__ O) {
    __shared__ u16 lds_all[24576];           // 48 KB: 3 x 16KB K/V rotation
    int tid = threadIdx.x, lane = tid & 63, wid = tid >> 6;
    int l15 = lane & 15, quad = lane >> 4;
    int sw = l15 & 7;
    int h = blockIdx.y;
    int q0 = blockIdx.x * 128 + wid * 32;
    const u16* Qh = Q + (size_t)h * N_TOK * DHEAD;
    const u16* Kh = K + (size_t)h * N_TOK * DHEAD;
    const u16* Vh = Vt + (size_t)h * DHEAD * N_TOK;

    f32x4 zero4 = {0.f, 0.f, 0.f, 0.f};
    bf16x8 ones;
#pragma unroll
    for (int i = 0; i < 8; ++i) ones[i] = (short)0x3F80;  // bf16 1.0

    // Q fragments (B operand): B[n=q=l15][k=dhead]
    bf16x8 aq[2][2];
#pragma unroll
    for (int mtQ = 0; mtQ < 2; ++mtQ)
#pragma unroll
        for (int kc = 0; kc < 2; ++kc)
            aq[mtQ][kc] = *(const bf16x8*)&Qh[(size_t)(q0 + mtQ * 16 + l15) * DHEAD + kc * 32 + quad * 8];

    f32x4 o[2][4], lacc[2];
#pragma unroll
    for (int mtQ = 0; mtQ < 2; ++mtQ) {
#pragma unroll
        for (int dt = 0; dt < 4; ++dt) o[mtQ][dt] = zero4;
        lacc[mtQ] = zero4;
    }

    // staging: wave stages K rows [wid*16, wid*16+16) and V rows same range
    int rowoff = lane >> 3;                      // 0..7
    int krow = wid * 16 + rowoff;                // 0..63 (with +8 variant)
    int kbase = wid * 1024;                      // u16: wid*16 rows * 64
    int csw = ((lane & 7) ^ rowoff) * 8;         // swizzled source column (u16)

    bf16x8 bk[4][2], avA[4][2], avB[4][2];
    f32x4 sA[2][4], sB[2][4];

    // prologue: stage tiles 0,1 -> bufs 0,1; wait tile0
    FA_STAGE3(0, 0);
    FA_STAGE3(8192, 64);
    VM4;
    __builtin_amdgcn_s_barrier();
    __builtin_amdgcn_sched_barrier(0);

    // t = 0 (A-half, no prev): read buf0, stage tile2, QK only
    FA_READ(0, avA);
    FA_STAGE3(16384, 128);
    LGK8F;
    FA_QK(sA);
    LGK0F;
    VM4;
    __builtin_amdgcn_s_barrier();
    __builtin_amdgcn_sched_barrier(0);

    int cur = 8192;
    for (int i = 0; i < 31; ++i) {
        int tB = 2 * i + 1, tA = 2 * i + 2;
        // B-half: tile tB; SM+PV of tile tB-1 (sA, avA)
        FA_READ(cur, avB);
        { int stg = cur + 16384; if (stg >= 24576) stg -= 24576;
          FA_STAGE3(stg, (tB + 2) * 64); }               // tB+2 <= 63 always
        LGK8F;
        FA_QK(sB);
        FA_SMPV(sA, avA);
        LGK0F;
        VM4;
        __builtin_amdgcn_s_barrier();
        __builtin_amdgcn_sched_barrier(0);
        cur += 8192; if (cur >= 24576) cur -= 24576;
        // A-half: tile tA; SM+PV of tile tA-1 (sB, avB)
        FA_READ(cur, avA);
        if (tA + 2 < 64) { int stg = cur + 16384; if (stg >= 24576) stg -= 24576;
                           FA_STAGE3(stg, (tA + 2) * 64); }
        LGK8F;
        FA_QK(sA);
        FA_SMPV(sB, avB);
        LGK0F;
        if (tA + 2 < 64) { VM4; } else { VM0; }          // tA=62: drain tile63
        __builtin_amdgcn_s_barrier();
        __builtin_amdgcn_sched_barrier(0);
        cur += 8192; if (cur >= 24576) cur -= 24576;
    }
    // tail: tile 63 (B-half role; nothing in flight)
    FA_READ(cur, avB);
    LGK8F;
    FA_QK(sB);
    FA_SMPV(sA, avA);
    LGK0F;
    FA_SMPV(sB, avB);

    // epilogue: transpose O^T -> O via per-wave LDS scratch, then coalesced write
    __syncthreads();
    u16* scratch = lds_all + wid * 2048;     // [q 32][d 64] per wave (4 KB)
#pragma unroll
    for (int mtQ = 0; mtQ < 2; ++mtQ) {
        float rl = 1.f / lacc[mtQ][0];
#pragma unroll
        for (int dt = 0; dt < 4; ++dt) {
            uint2 ov;
            ov.x = pk2bf(o[mtQ][dt][0] * rl, o[mtQ][dt][1] * rl);
            ov.y = pk2bf(o[mtQ][dt][2] * rl, o[mtQ][dt][3] * rl);
            *(uint2*)&scratch[(mtQ * 16 + l15) * 64 + dt * 16 + quad * 4] = ov;
        }
    }
    __syncthreads();
#pragma unroll
    for (int p = 0; p < 4; ++p) {
        int q_local = p * 8 + (lane >> 3);
        int dcol = (lane & 7) * 8;
        bf16x8 v = *(const bf16x8*)&scratch[q_local * 64 + dcol];
        *(bf16x8*)&O[(size_t)(q0 + q_local) * INNER + h * 64 + dcol] = v;
    }
}

extern "C" void kernel_launch(void* const* d_in, const int* in_sizes, int n_in,
                              void* d_out, int out_size, void* d_ws, size_t ws_size,
                              hipStream_t stream) {
    const float* x     = (const float*)d_in[0];
    const float* pe    = (const float*)d_in[1];
    const float* w_qkv = (const float*)d_in[2];
    const float* w_out = (const float*)d_in[3];
    const float* ln_g  = (const float*)d_in[4];
    const float* ln_b  = (const float*)d_in[5];
    float* out = (float*)d_out;

    char* ws = (char*)d_ws;
    u16* xn  = (u16*)ws;  ws += (size_t)N_TOK * DMODEL * 2;
    u16* wq  = (u16*)ws;  ws += (size_t)3 * INNER * DMODEL * 2;
    u16* wo  = (u16*)ws;  ws += (size_t)DMODEL * INNER * 2;
    u16* Qr  = (u16*)ws;  ws += (size_t)NH * N_TOK * DHEAD * 2;
    u16* Kr  = (u16*)ws;  ws += (size_t)NH * N_TOK * DHEAD * 2;
    u16* Vt  = (u16*)ws;  ws += (size_t)NH * DHEAD * N_TOK * 2;
    u16* Ob  = (u16*)ws;  ws += (size_t)N_TOK * INNER * 2;

    prep<<<4096 + 2048 + 512, 256, 0, stream>>>(x, ln_g, ln_b, xn, w_qkv, wq, w_out, wo);
    gemm256<2><<<dim3((N_TOK / 256) * (DMODEL / 192)), 512, 0, stream>>>(
        xn, wq, nullptr, N_TOK, DMODEL, DMODEL, pe, Qr, Kr, Vt);
    flash_attn<<<dim3(N_TOK / 128, NH), 256, 0, stream>>>(Qr, Kr, Vt, Ob);
    gemm256<0><<<dim3((N_TOK / 256) * (DMODEL / 192)), 512, 0, stream>>>(
        Ob, wo, out, N_TOK, DMODEL, INNER, nullptr, nullptr, nullptr, nullptr);
}